// Round 19
// baseline (428.739 us; speedup 1.0000x reference)
//
#include <hip/hip_runtime.h>
#include <hip/hip_bf16.h>
#include <math.h>

#define BATCH 1024
#define LABEL 128
#define LATENT 512
#define NTOT 1152  // 1024 + 128

typedef short short8 __attribute__((ext_vector_type(8)));
typedef float f32x16 __attribute__((ext_vector_type(16)));

__device__ __forceinline__ unsigned short f2bf(float f) {
    __hip_bfloat16 h = __float2bfloat16(f);
    return *(unsigned short*)&h;
}
__device__ __forceinline__ float bf2f(unsigned short u) {
    __hip_bfloat16 h; *(unsigned short*)&h = u;
    return __bfloat162float(h);
}

#define BSTR ((size_t)512 * 3136)
#define ASTR ((size_t)NTOT * 3136)
#define A2STR ((size_t)BATCH * 512)
#define W2STR ((size_t)LABEL * 512)

// NUMERICS RULE (r15/r17): w_kernel/rho keep r14-exact op order.
// COVERAGE RULE (r16): conv1 writes all 196 pixels (xh loop).
// r19: Hopfield k=1 hoisted into GEMMs (s1init/h1init); clustering starts k=2.

// ------- conv1 v3 (r17 proven) ------------------------------------------------
__global__ __launch_bounds__(256) void conv1_pool(const float* __restrict__ image,
                                                  const float* __restrict__ limg,
                                                  const float* __restrict__ wt,
                                                  const float* __restrict__ bias,
                                                  unsigned short* __restrict__ o1b) {
    const int n = blockIdx.x;
    const float* in = (n < BATCH) ? (image + (size_t)n * 784)
                                  : (limg + (size_t)(n - BATCH) * 784);
    __shared__ float pin[32][32];
    __shared__ float wts[32 * 25];
    const int tid = threadIdx.x;
    unsigned short* ob = o1b + (size_t)n * 12800;
    for (int i = tid; i < 256; i += 256) {
        int pl_ = i >> 7, r = i & 127;
        ob[pl_ * 6400 + 6272 + r] = 0;
    }
    for (int idx = tid; idx < 32 * 32; idx += 256) ((float*)pin)[idx] = 0.f;
    __syncthreads();
    for (int idx = tid; idx < 784; idx += 256) {
        int y = idx / 28, x = idx % 28;
        pin[y + 2][x + 2] = in[idx];
    }
    for (int idx = tid; idx < 800; idx += 256) wts[idx] = wt[idx];
    __syncthreads();
    const int oc = tid & 31;
    float wk[25];
    #pragma unroll
    for (int k = 0; k < 25; ++k) wk[k] = wts[oc * 25 + k];
    const float b = bias[oc];
    const int slot_lo = (oc & 7);
    const int gq = oc >> 3;
    for (int it = 0; it < 2; ++it) {
        const int py = (tid >> 5) + it * 8;
        if (py >= 14) continue;
        #pragma unroll
        for (int xh = 0; xh < 2; ++xh) {
            const int acol = xh ? 12 : 0;
            const int off = xh ? 2 : 0;
            float a0[14], a1[14];
            #pragma unroll
            for (int c = 0; c < 14; ++c) { a0[c] = b; a1[c] = b; }
            #pragma unroll
            for (int t = 0; t < 6; ++t) {
                float row[20];
                const float4* rp = (const float4*)&pin[2 * py + t][acol];
                #pragma unroll
                for (int v = 0; v < 5; ++v) {
                    float4 f = rp[v];
                    row[4 * v] = f.x; row[4 * v + 1] = f.y;
                    row[4 * v + 2] = f.z; row[4 * v + 3] = f.w;
                }
                if (t < 5) {
                    #pragma unroll
                    for (int kx = 0; kx < 5; ++kx) {
                        float w0 = wk[t * 5 + kx];
                        #pragma unroll
                        for (int c = 0; c < 14; ++c)
                            a0[c] = fmaf(row[c + kx + off], w0, a0[c]);
                    }
                }
                if (t >= 1) {
                    #pragma unroll
                    for (int kx = 0; kx < 5; ++kx) {
                        float w1 = wk[(t - 1) * 5 + kx];
                        #pragma unroll
                        for (int c = 0; c < 14; ++c)
                            a1[c] = fmaf(row[c + kx + off], w1, a1[c]);
                    }
                }
            }
            #pragma unroll
            for (int px = 0; px < 7; ++px) {
                float v = fmaxf(fmaxf(a0[2 * px], a0[2 * px + 1]),
                                fmaxf(a1[2 * px], a1[2 * px + 1]));
                v = fmaxf(v, 0.f);
                unsigned short b1 = f2bf(v);
                unsigned short b2 = f2bf(v - bf2f(b1));
                int p = py * 14 + 7 * xh + px;
                int offo = p * 32 + (((gq ^ (p >> 1)) & 3) << 3) + slot_lo;
                ob[offo] = b1; ob[6400 + offo] = b2;
            }
        }
    }
}

// ------- merged prep (r17 proven) ---------------------------------------------
__global__ __launch_bounds__(256) void prep(const float* __restrict__ c2w,
                                            const float* __restrict__ f1w,
                                            const float* __restrict__ fnw,
                                            unsigned short* __restrict__ Bf,
                                            unsigned short* __restrict__ Bw2,
                                            unsigned short* __restrict__ Bn2) {
    int idx = blockIdx.x * 256 + threadIdx.x;
    if (idx < 102400) {
        int j = idx & 7, lane = (idx >> 3) & 63, ocT = (idx >> 9) & 1, s = idx >> 10;
        int q = lane >> 5, nn = lane & 31;
        int k = 16 * s + 8 * q + j;
        int tap = k >> 5, ic = k & 31;
        int oc = 32 * ocT + nn;
        float v = c2w[oc * 800 + ic * 25 + tap];
        unsigned short b1 = f2bf(v);
        unsigned short b2 = f2bf(v - bf2f(b1));
        size_t base = ((size_t)(s * 2 + ocT) * 2) * 512 + lane * 8 + j;
        Bf[base] = b1; Bf[base + 512] = b2;
        return;
    }
    int i2 = idx - 102400;
    if (i2 < 512 * 3136) {
        float v = f1w[i2];
        unsigned short b1 = f2bf(v);
        unsigned short b2 = f2bf(v - bf2f(b1));
        Bw2[i2] = b1; Bw2[BSTR + i2] = b2;
        return;
    }
    int i3 = i2 - 512 * 3136;
    if (i3 >= 128 * 512) return;
    float v = fnw[i3];
    unsigned short b1 = f2bf(v);
    unsigned short b2 = f2bf(v - bf2f(b1));
    Bn2[i3] = b1; Bn2[W2STR + i3] = b2;
}

// ------- conv2 via MFMA, v7 (r13 proven, unchanged) ---------------------------
__global__ __launch_bounds__(256) void conv2_mfma(const unsigned short* __restrict__ o1b,
                                                  const unsigned short* __restrict__ Bf,
                                                  const float* __restrict__ bias,
                                                  unsigned short* __restrict__ out2) {
    const int n = blockIdx.x;
    __shared__ __align__(16) unsigned short pl[12800];
    const int tid = threadIdx.x;
    const int lane = tid & 63, wv = tid >> 6;
    const int ocT = wv & 1, mh = wv >> 1;

    {
        const float4* src = (const float4*)(o1b + (size_t)n * 12800);
        float4* dst = (float4*)pl;
        for (int i = tid; i < 1600; i += 256) dst[i] = src[i];
    }
    __syncthreads();

    const int m_ = lane & 31, q = lane >> 5;
    int ym[4], xm[4], mm[4], tvv[4];
    #pragma unroll
    for (int tt = 0; tt < 4; ++tt) {
        int t = 4 * mh + tt;
        tvv[tt] = (t < 7);
        int m = 32 * t + m_;
        mm[tt] = m;
        ym[tt] = m / 14;
        xm[tt] = m - 14 * ym[tt];
    }
    f32x16 acc[4];
    {
        float bs = bias[32 * ocT + m_];
        #pragma unroll
        for (int tt = 0; tt < 4; ++tt)
        #pragma unroll
        for (int r = 0; r < 16; ++r) acc[tt][r] = bs;
    }

    for (int s = 0; s < 50; ++s) {
        const unsigned short* bp = Bf + ((size_t)(s * 2 + ocT) * 2) * 512 + lane * 8;
        short8 b1 = *(const short8*)(bp);
        short8 b2 = *(const short8*)(bp + 512);
        int kb = 16 * s + 8 * q;
        int tap = kb >> 5, ic0 = kb & 31, g = ic0 >> 3;
        int ky = (tap * 13) >> 6;
        int kx = tap - ky * 5;
        int iyk = ky - 2, ixk = kx - 2;
        int pq2 = iyk * 14 + ixk;
        short8 a1[4], a2[4];
        #pragma unroll
        for (int tt = 0; tt < 4; ++tt) {
            int iy = ym[tt] + iyk, ix = xm[tt] + ixk;
            int valid = tvv[tt] & ((unsigned)iy < 14u) & ((unsigned)ix < 14u);
            int cpt = valid ? (mm[tt] + pq2) : 196;
            int addr = cpt * 32 + (((g ^ (cpt >> 1)) & 3) << 3);
            a1[tt] = *(const short8*)(pl + addr);
            a2[tt] = *(const short8*)(pl + 6400 + addr);
        }
        #pragma unroll
        for (int tt = 0; tt < 4; ++tt)
            acc[tt] = __builtin_amdgcn_mfma_f32_32x32x16_bf16(a1[tt], b1, acc[tt], 0, 0, 0);
        #pragma unroll
        for (int tt = 0; tt < 4; ++tt)
            acc[tt] = __builtin_amdgcn_mfma_f32_32x32x16_bf16(a1[tt], b2, acc[tt], 0, 0, 0);
        #pragma unroll
        for (int tt = 0; tt < 4; ++tt)
            acc[tt] = __builtin_amdgcn_mfma_f32_32x32x16_bf16(a2[tt], b1, acc[tt], 0, 0, 0);
    }
    __syncthreads();

    float* hx = (float*)pl;
    {
        const int oc = 32 * ocT + m_;
        #pragma unroll
        for (int tt = 0; tt < 4; ++tt)
        #pragma unroll
        for (int e = 0; e < 8; ++e) {
            const int reg = 2 * e;
            const int r = (reg & 3) + 8 * (reg >> 2) + 4 * q;
            const int m = 32 * (4 * mh + tt) + r;
            if (m < 196) {
                float xm2 = fmaxf(acc[tt][reg], acc[tt][reg + 1]);
                int y = (m * 2341) >> 15;
                int px = (m - 14 * y) >> 1;
                hx[(y * 7 + px) * 65 + oc] = xm2;
            }
        }
    }
    __syncthreads();

    for (int idx = tid; idx < 3136; idx += 256) {
        int oc2 = (idx * 2675) >> 17;
        int p = idx - 49 * oc2;
        int py = (p * 9363) >> 16;
        int px = p - 7 * py;
        float v = fmaxf(hx[(2 * py * 7 + px) * 65 + oc2],
                        hx[((2 * py + 1) * 7 + px) * 65 + oc2]);
        v = fmaxf(v, 0.f);
        unsigned short b1 = f2bf(v);
        unsigned short b2 = f2bf(v - bf2f(b1));
        size_t o = (size_t)n * 3136 + idx;
        out2[o] = b1; out2[ASTR + o] = b2;
    }
}

// ------- fc1 via MFMA (r14 proven) --------------------------------------------
__global__ __launch_bounds__(256) void fc1_mfma(const unsigned short* __restrict__ A2,
                                                const unsigned short* __restrict__ B2,
                                                float* __restrict__ part) {
    __shared__ unsigned short As[2][2048];
    __shared__ unsigned short Bs[2][2048];
    const int tid = threadIdx.x;
    const int n0 = blockIdx.x * 64, m0 = blockIdx.y * 64;
    const int koff = blockIdx.z * 448;
    const int lr = tid >> 2, g = tid & 3;
    const int slot = (((g ^ (lr >> 1)) & 3) << 3);
    const int lane = tid & 63, wv = tid >> 6;
    const int nq = wv & 1, mq = wv >> 1;
    const int q = lane >> 5, l31 = lane & 31;
    const int rA = 32 * nq + l31, rB = 32 * mq + l31;
    f32x16 acc;
    #pragma unroll
    for (int r = 0; r < 16; ++r) acc[r] = 0.f;

    for (int bk = 0; bk < 448; bk += 32) {
        const size_t ka = (size_t)(koff + bk + (g << 3));
        short8 av[2], bv[2];
        #pragma unroll
        for (int p = 0; p < 2; ++p) {
            av[p] = *(const short8*)(A2 + p * ASTR + (size_t)(n0 + lr) * 3136 + ka);
            bv[p] = *(const short8*)(B2 + p * BSTR + (size_t)(m0 + lr) * 3136 + ka);
        }
        __syncthreads();
        #pragma unroll
        for (int p = 0; p < 2; ++p) {
            *(short8*)&As[p][(lr << 5) + slot] = av[p];
            *(short8*)&Bs[p][(lr << 5) + slot] = bv[p];
        }
        __syncthreads();
        #pragma unroll
        for (int s2 = 0; s2 < 32; s2 += 16) {
            const int gg = (s2 + (q << 3)) >> 3;
            const int sa = (((gg ^ (rA >> 1)) & 3) << 3);
            const int sb = (((gg ^ (rB >> 1)) & 3) << 3);
            short8 a1 = *(const short8*)&As[0][(rA << 5) + sa];
            short8 a2 = *(const short8*)&As[1][(rA << 5) + sa];
            short8 b1 = *(const short8*)&Bs[0][(rB << 5) + sb];
            short8 b2 = *(const short8*)&Bs[1][(rB << 5) + sb];
            acc = __builtin_amdgcn_mfma_f32_32x32x16_bf16(a1, b1, acc, 0, 0, 0);
            acc = __builtin_amdgcn_mfma_f32_32x32x16_bf16(a1, b2, acc, 0, 0, 0);
            acc = __builtin_amdgcn_mfma_f32_32x32x16_bf16(a2, b1, acc, 0, 0, 0);
        }
    }
    float* pb = part + (size_t)blockIdx.z * NTOT * 512;
    #pragma unroll
    for (int reg = 0; reg < 16; ++reg) {
        int nn = n0 + 32 * nq + (reg & 3) + 8 * (reg >> 2) + 4 * q;
        int mmo = m0 + 32 * mq + l31;
        pb[(size_t)nn * 512 + mmo] = acc[reg];
    }
}

__global__ __launch_bounds__(256) void fc1_reduce(const float* __restrict__ part,
                                                  const float* __restrict__ bias,
                                                  float* __restrict__ lat,
                                                  unsigned short* __restrict__ lat2,
                                                  float* __restrict__ rep) {
    int idx = blockIdx.x * 256 + threadIdx.x;
    int m = idx & 511;
    float v = bias[m];
    #pragma unroll
    for (int kz = 0; kz < 7; ++kz) v += part[(size_t)kz * NTOT * 512 + idx];
    if (idx < BATCH * 512) {
        lat[idx] = v;
        unsigned short b1 = f2bf(v);
        lat2[idx] = b1;
        lat2[A2STR + idx] = f2bf(v - bf2f(b1));
    } else {
        rep[idx - BATCH * 512] = tanhf(v);
    }
}

// ------- fcn fused: logits via MFMA + softmax, one 64x128 tile per block ------
__global__ __launch_bounds__(256) void fcn_fused(const unsigned short* __restrict__ A2,
                                                 const unsigned short* __restrict__ B2,
                                                 const float* __restrict__ fb,
                                                 float* __restrict__ out) {
    __shared__ unsigned short As[2][2048];
    __shared__ unsigned short Bs[2][4096];
    __shared__ float Ls[64][132];
    __shared__ float fbs[128], rmax[64], rsum[64];
    const int tid = threadIdx.x;
    const int n0 = blockIdx.x * 64;
    const int lr = tid >> 2, g = tid & 3;
    const int slotA = (((g ^ (lr >> 1)) & 3) << 3);
    const int lrB2 = lr + 64;
    const int slotB2 = (((g ^ (lrB2 >> 1)) & 3) << 3);
    const int lane = tid & 63, wv = tid >> 6;
    const int nq = wv & 1, mq = wv >> 1;
    const int q = lane >> 5, l31 = lane & 31;
    const int rA = 32 * nq + l31;
    if (tid < 128) fbs[tid] = fb[tid];
    f32x16 acc[2];
    #pragma unroll
    for (int j = 0; j < 2; ++j)
    #pragma unroll
    for (int r = 0; r < 16; ++r) acc[j][r] = 0.f;

    for (int bk = 0; bk < 512; bk += 32) {
        const size_t ka = (size_t)(bk + (g << 3));
        short8 av[2], blo[2], bhi[2];
        #pragma unroll
        for (int p = 0; p < 2; ++p) {
            av[p]  = *(const short8*)(A2 + p * A2STR + (size_t)(n0 + lr) * 512 + ka);
            blo[p] = *(const short8*)(B2 + p * W2STR + (size_t)lr * 512 + ka);
            bhi[p] = *(const short8*)(B2 + p * W2STR + (size_t)lrB2 * 512 + ka);
        }
        __syncthreads();
        #pragma unroll
        for (int p = 0; p < 2; ++p) {
            *(short8*)&As[p][(lr << 5) + slotA] = av[p];
            *(short8*)&Bs[p][(lr << 5) + slotA] = blo[p];
            *(short8*)&Bs[p][(lrB2 << 5) + slotB2] = bhi[p];
        }
        __syncthreads();
        #pragma unroll
        for (int s2 = 0; s2 < 32; s2 += 16) {
            const int gg = (s2 + (q << 3)) >> 3;
            const int sa = (((gg ^ (rA >> 1)) & 3) << 3);
            short8 a1 = *(const short8*)&As[0][(rA << 5) + sa];
            short8 a2 = *(const short8*)&As[1][(rA << 5) + sa];
            #pragma unroll
            for (int j = 0; j < 2; ++j) {
                const int rB = 64 * mq + 32 * j + l31;
                const int sb = (((gg ^ (rB >> 1)) & 3) << 3);
                short8 b1 = *(const short8*)&Bs[0][(rB << 5) + sb];
                short8 b2 = *(const short8*)&Bs[1][(rB << 5) + sb];
                acc[j] = __builtin_amdgcn_mfma_f32_32x32x16_bf16(a1, b1, acc[j], 0, 0, 0);
                acc[j] = __builtin_amdgcn_mfma_f32_32x32x16_bf16(a1, b2, acc[j], 0, 0, 0);
                acc[j] = __builtin_amdgcn_mfma_f32_32x32x16_bf16(a2, b1, acc[j], 0, 0, 0);
            }
        }
    }
    __syncthreads();
    #pragma unroll
    for (int j = 0; j < 2; ++j)
    #pragma unroll
    for (int reg = 0; reg < 16; ++reg) {
        int nnl = 32 * nq + (reg & 3) + 8 * (reg >> 2) + 4 * q;
        int mml = 64 * mq + 32 * j + l31;
        Ls[nnl][mml] = acc[j][reg];
    }
    __syncthreads();
    if (tid < 64) {
        float mx = -1e30f;
        for (int c = 0; c < 128; ++c) mx = fmaxf(mx, Ls[tid][c] + fbs[c]);
        float sm = 0.f;
        for (int c = 0; c < 128; ++c) sm += expf(Ls[tid][c] + fbs[c] - mx);
        rmax[tid] = mx; rsum[tid] = sm;
    }
    __syncthreads();
    for (int i = tid; i < 8192; i += 256) {
        int r = i >> 7, c = i & 127;
        out[(size_t)(n0 + r) * 128 + c] =
            expf(Ls[r][c] + fbs[c] - rmax[r]) / rsum[r];
    }
}

// ------- rho (r14-exact) ------------------------------------------------------
__global__ __launch_bounds__(256) void rho_kernel(const float* __restrict__ rep,
                                                  float* __restrict__ rho) {
    __shared__ float red[256];
    const int tid = threadIdx.x;
    float s = 0.f;
    for (int i = tid; i < LABEL * LATENT; i += 256) s += rep[i];
    red[tid] = s;
    __syncthreads();
    for (int off = 128; off >= 1; off >>= 1) {
        if (tid < off) red[tid] += red[tid + off];
        __syncthreads();
    }
    if (tid == 0) rho[0] = red[0] / (float)(LABEL * LATENT);
}

// ------- t v2 (r18 proven, elementwise transpose) -----------------------------
__global__ __launch_bounds__(256) void t_kernel(const float* __restrict__ rep,
                                                const float* __restrict__ rho,
                                                float* __restrict__ tT) {
    __shared__ float tile[64][65];
    const int tid = threadIdx.x;
    const int i0 = blockIdx.x * 64, k0 = blockIdx.y * 64;
    const int tx = tid & 63, ty4 = tid >> 6;
    const float r0 = rho[0];
    #pragma unroll
    for (int rr = 0; rr < 16; ++rr) {
        int kk = ty4 * 16 + rr;
        tile[kk][tx] = rep[(size_t)(k0 + kk) * 512 + i0 + tx];
    }
    __syncthreads();
    #pragma unroll
    for (int rr = 0; rr < 16; ++rr) {
        int ii = ty4 * 16 + rr;
        tT[(size_t)(i0 + ii) * 128 + k0 + tx] = tile[tx][ii] - r0;
    }
}

// ------- w_kernel: r14-EXACT --------------------------------------------------
__global__ __launch_bounds__(256) void w_kernel(const float* __restrict__ tT,
                                                float* __restrict__ w) {
    int idx = blockIdx.x * 256 + threadIdx.x;
    int i = idx >> 9, j = idx & 511;
    const float4* a = (const float4*)(tT + i * 128);
    const float4* b = (const float4*)(tT + j * 128);
    float acc = 0.f;
    #pragma unroll 8
    for (int q = 0; q < 32; ++q) {
        float4 av = a[q], bv = b[q];
        acc += av.x * bv.x + av.y * bv.y + av.z * bv.z + av.w * bv.w;
    }
    w[idx] = (i == j) ? 0.f : acc * (1.f / 128.f);
}

// ------- s1init: h0 = tanh(lat)@w, epilogue writes s1 = |s0|*sign(h0) ---------
__device__ __forceinline__ float sgnf(float x) {
    return (x > 0.f) ? 1.f : ((x < 0.f) ? -1.f : 0.f);
}

__global__ __launch_bounds__(256) void s1init(const float* __restrict__ lat,
                                              const float* __restrict__ w,
                                              float* __restrict__ s1buf) {
    __shared__ float As[16][68];
    __shared__ float Bs[16][68];
    const int tid = threadIdx.x;
    const int n0 = blockIdx.x * 64, m0 = blockIdx.y * 64;
    const int lr = tid >> 2;
    const int lk = (tid & 3) * 4;
    const int ty = tid >> 4, tx = tid & 15;
    float c[4][4] = {};
    for (int k0 = 0; k0 < 512; k0 += 16) {
        float4 a4 = *(const float4*)(lat + (size_t)(n0 + lr) * 512 + k0 + lk);
        float4 b4 = *(const float4*)(w + (size_t)(m0 + lr) * 512 + k0 + lk);
        a4.x = tanhf(a4.x); a4.y = tanhf(a4.y); a4.z = tanhf(a4.z); a4.w = tanhf(a4.w);
        __syncthreads();
        As[lk + 0][lr] = a4.x; As[lk + 1][lr] = a4.y; As[lk + 2][lr] = a4.z; As[lk + 3][lr] = a4.w;
        Bs[lk + 0][lr] = b4.x; Bs[lk + 1][lr] = b4.y; Bs[lk + 2][lr] = b4.z; Bs[lk + 3][lr] = b4.w;
        __syncthreads();
        #pragma unroll
        for (int kk = 0; kk < 16; ++kk) {
            float av[4], bv[4];
            #pragma unroll
            for (int i = 0; i < 4; ++i) av[i] = As[kk][ty * 4 + i];
            #pragma unroll
            for (int j = 0; j < 4; ++j) bv[j] = Bs[kk][tx * 4 + j];
            #pragma unroll
            for (int i = 0; i < 4; ++i)
            #pragma unroll
            for (int j = 0; j < 4; ++j) c[i][j] += av[i] * bv[j];
        }
    }
    #pragma unroll
    for (int i = 0; i < 4; ++i) {
        const int nn = n0 + ty * 4 + i;
        float4 lv = *(const float4*)(lat + (size_t)nn * 512 + m0 + tx * 4);
        float s0a[4] = {tanhf(lv.x), tanhf(lv.y), tanhf(lv.z), tanhf(lv.w)};
        #pragma unroll
        for (int j = 0; j < 4; ++j)
            s1buf[(size_t)nn * 512 + m0 + tx * 4 + j] = fabsf(s0a[j]) * sgnf(c[i][j]);
    }
}

// ------- h1init: hmat2 = s1buf @ w --------------------------------------------
__global__ __launch_bounds__(256) void h1init(const float* __restrict__ s1buf,
                                              const float* __restrict__ w,
                                              float* __restrict__ hmat2) {
    __shared__ float As[16][68];
    __shared__ float Bs[16][68];
    const int tid = threadIdx.x;
    const int n0 = blockIdx.x * 64, m0 = blockIdx.y * 64;
    const int lr = tid >> 2;
    const int lk = (tid & 3) * 4;
    const int ty = tid >> 4, tx = tid & 15;
    float c[4][4] = {};
    for (int k0 = 0; k0 < 512; k0 += 16) {
        float4 a4 = *(const float4*)(s1buf + (size_t)(n0 + lr) * 512 + k0 + lk);
        float4 b4 = *(const float4*)(w + (size_t)(m0 + lr) * 512 + k0 + lk);
        __syncthreads();
        As[lk + 0][lr] = a4.x; As[lk + 1][lr] = a4.y; As[lk + 2][lr] = a4.z; As[lk + 3][lr] = a4.w;
        Bs[lk + 0][lr] = b4.x; Bs[lk + 1][lr] = b4.y; Bs[lk + 2][lr] = b4.z; Bs[lk + 3][lr] = b4.w;
        __syncthreads();
        #pragma unroll
        for (int kk = 0; kk < 16; ++kk) {
            float av[4], bv[4];
            #pragma unroll
            for (int i = 0; i < 4; ++i) av[i] = As[kk][ty * 4 + i];
            #pragma unroll
            for (int j = 0; j < 4; ++j) bv[j] = Bs[kk][tx * 4 + j];
            #pragma unroll
            for (int i = 0; i < 4; ++i)
            #pragma unroll
            for (int j = 0; j < 4; ++j) c[i][j] += av[i] * bv[j];
        }
    }
    #pragma unroll
    for (int i = 0; i < 4; ++i)
    #pragma unroll
    for (int j = 0; j < 4; ++j)
        hmat2[(size_t)(n0 + ty * 4 + i) * 512 + m0 + tx * 4 + j] = c[i][j];
}

// ------- clustering v4: starts at k=2 (k=1 hoisted into s1init/h1init) --------
__global__ __launch_bounds__(256) void clustering(const float* __restrict__ lat,
                                                  const float* __restrict__ s1buf,
                                                  const float* __restrict__ hmat2,
                                                  const float* __restrict__ w,
                                                  const float* __restrict__ rep,
                                                  float* __restrict__ out) {
    const int tid = threadIdx.x;
    const int row = blockIdx.x;
    __shared__ float mins[512];
    __shared__ float red[256];
    __shared__ float part_e[4];
    __shared__ int part_c[4];
    __shared__ float min_e_s;
    __shared__ int copyf_s;
    __shared__ int donef_s;
    __shared__ int cnt_s;
    __shared__ int jidx[512];
    __shared__ float jdel[512];
    const int i0 = 2 * tid, i1 = 2 * tid + 1;
    const int wave = tid >> 6, lane = tid & 63;

    // state entering k=2: sm2 = s0, sm1 = s1, h = h1 = W s1
    float sm20 = tanhf(lat[(size_t)row * 512 + i0]);
    float sm21 = tanhf(lat[(size_t)row * 512 + i1]);
    float sm10 = s1buf[(size_t)row * 512 + i0];
    float sm11 = s1buf[(size_t)row * 512 + i1];
    float h0 = hmat2[(size_t)row * 512 + i0];
    float h1 = hmat2[(size_t)row * 512 + i1];
    // k=1 min tracking: min_e = e1 = -(s1 . h1), min_s = s1
    mins[i0] = sm10; mins[i1] = sm11;
    {
        float ep = sm10 * h0 + sm11 * h1;
        #pragma unroll
        for (int m = 32; m >= 1; m >>= 1) ep += __shfl_xor(ep, m, 64);
        if (lane == 0) part_e[wave] = ep;
    }
    if (tid == 0) { donef_s = 0; cnt_s = 0; }
    __syncthreads();
    if (tid == 0) min_e_s = -(part_e[0] + part_e[1] + part_e[2] + part_e[3]);
    __syncthreads();

    for (int k = 2; k <= 512; ++k) {
        float sn0 = fabsf(sm10) * sgnf(h0);
        float sn1 = fabsf(sm11) * sgnf(h1);
        int cy = (sn0 == sm20 && sn1 == sm21) ? 1 : 0;
        if (sn0 != sm10) {
            int p = atomicAdd(&cnt_s, 1);
            jidx[p] = i0; jdel[p] = sn0 - sm10;
        }
        if (sn1 != sm11) {
            int p = atomicAdd(&cnt_s, 1);
            jidx[p] = i1; jdel[p] = sn1 - sm11;
        }
        #pragma unroll
        for (int m = 32; m >= 1; m >>= 1) cy &= __shfl_xor(cy, m, 64);
        if (lane == 0) part_c[wave] = cy;
        __syncthreads();

        {
            const int c = cnt_s;
            #pragma unroll 8
            for (int t = 0; t < c; ++t) {
                const int j = jidx[t];
                const float d = jdel[t];
                const float2 wvv = *(const float2*)(w + (size_t)j * 512 + i0);
                h0 = fmaf(d, wvv.x, h0);
                h1 = fmaf(d, wvv.y, h1);
            }
        }
        float ep = sn0 * h0 + sn1 * h1;
        #pragma unroll
        for (int m = 32; m >= 1; m >>= 1) ep += __shfl_xor(ep, m, 64);
        if (lane == 0) part_e[wave] = ep;
        __syncthreads();

        if (tid == 0) {
            float e = -(part_e[0] + part_e[1] + part_e[2] + part_e[3]);
            int better = e < min_e_s;
            if (better) min_e_s = e;
            copyf_s = better;
            int fl = part_c[0] & part_c[1] & part_c[2] & part_c[3];
            int fixedp = (cnt_s == 0);
            if (fixedp || fl) donef_s = 1;
            cnt_s = 0;
        }
        __syncthreads();

        if (copyf_s) { mins[i0] = sn0; mins[i1] = sn1; }
        sm20 = sm10; sm21 = sm11;
        sm10 = sn0;  sm11 = sn1;
        if (donef_s) break;
    }
    __syncthreads();

    const int j = tid & 127, half = tid >> 7;
    {
        const float4* rr = (const float4*)(rep + (size_t)j * 512 + half * 256);
        const float4* ms = (const float4*)(&mins[half * 256]);
        float p = 0.f;
        #pragma unroll 8
        for (int q = 0; q < 64; ++q) {
            float4 rv = rr[q], mv = ms[q];
            p += rv.x * mv.x + rv.y * mv.y + rv.z * mv.z + rv.w * mv.w;
        }
        red[tid] = p;
        __syncthreads();
        float v = 0.f;
        if (tid < 128) { v = fabsf(red[tid] + red[tid + 128]); red[tid] = v; }
        __syncthreads();
        for (int off = 64; off >= 1; off >>= 1) {
            if (tid < off) red[tid] = fmaxf(red[tid], red[tid + off]);
            __syncthreads();
        }
        float mx = red[0];
        __syncthreads();
        float ex = 0.f;
        if (tid < 128) { ex = expf(v - mx); red[tid] = ex; }
        __syncthreads();
        for (int off = 64; off >= 1; off >>= 1) {
            if (tid < off) red[tid] += red[tid + off];
            __syncthreads();
        }
        if (tid < 128) out[(size_t)row * 128 + tid] = ex / red[0];
    }
}

extern "C" void kernel_launch(void* const* d_in, const int* in_sizes, int n_in,
                              void* d_out, int out_size, void* d_ws, size_t ws_size,
                              hipStream_t stream) {
    const float* image = (const float*)d_in[0];
    const float* limg  = (const float*)d_in[1];
    const float* c1w   = (const float*)d_in[2];
    const float* c1b   = (const float*)d_in[3];
    const float* c2w   = (const float*)d_in[4];
    const float* c2b   = (const float*)d_in[5];
    const float* f1w   = (const float*)d_in[6];
    const float* f1b   = (const float*)d_in[7];
    const float* fnw   = (const float*)d_in[8];
    const float* fnb   = (const float*)d_in[9];
    float* out = (float*)d_out;
    float* ws  = (float*)d_ws;

    unsigned short* o1b  = (unsigned short*)ws;        // 1152*12800 us
    unsigned short* out2 = o1b + (size_t)NTOT * 12800; // 2*ASTR bf16
    float* lat  = (float*)(out2 + 2 * ASTR);           // 1024*512
    float* rep  = lat + (size_t)BATCH * 512;           // 128*512
    float* tT   = rep + (size_t)LABEL * 512;           // 512*128
    float* wmat = tT + (size_t)512 * 128;              // 512*512
    float* rho  = wmat + (size_t)512 * 512;            // 1 (+pad)
    unsigned short* Bw2   = (unsigned short*)(rho + 16);   // 2*BSTR bf16
    unsigned short* Bfrag = Bw2 + 2 * BSTR;                // 102,400 bf16
    float* s1buf = (float*)(Bfrag + 102400);           // 1024*512 f32
    unsigned short* lat2 = (unsigned short*)(s1buf + A2STR);  // 2*A2STR bf16
    unsigned short* fnw2 = lat2 + 2 * A2STR;           // 2*W2STR bf16
    float* hmat2 = (float*)(fnw2 + 2 * W2STR);         // 1024*512 f32
    float* part = (float*)ws;                          // alias o1b (dead after conv2)

    const int prep_total = 102400 + 512 * 3136 + 128 * 512;
    hipLaunchKernelGGL(prep, dim3((prep_total + 255) / 256), dim3(256), 0, stream,
                       c2w, f1w, fnw, Bfrag, Bw2, fnw2);
    hipLaunchKernelGGL(conv1_pool, dim3(NTOT), dim3(256), 0, stream, image, limg, c1w, c1b, o1b);
    hipLaunchKernelGGL(conv2_mfma, dim3(NTOT), dim3(256), 0, stream, o1b, Bfrag, c2b, out2);
    hipLaunchKernelGGL(fc1_mfma, dim3(NTOT / 64, 512 / 64, 7), dim3(256), 0, stream,
                       out2, Bw2, part);
    hipLaunchKernelGGL(fc1_reduce, dim3(NTOT * 512 / 256), dim3(256), 0, stream,
                       part, f1b, lat, lat2, rep);
    hipLaunchKernelGGL(fcn_fused, dim3(BATCH / 64), dim3(256), 0, stream,
                       lat2, fnw2, fnb, out + (size_t)BATCH * LABEL);
    hipLaunchKernelGGL(rho_kernel, dim3(1), dim3(256), 0, stream, rep, rho);
    hipLaunchKernelGGL(t_kernel, dim3(8, 2), dim3(256), 0, stream, rep, rho, tT);
    hipLaunchKernelGGL(w_kernel, dim3(1024), dim3(256), 0, stream, tT, wmat);
    hipLaunchKernelGGL(s1init, dim3(BATCH / 64, 512 / 64), dim3(256), 0, stream,
                       lat, wmat, s1buf);
    hipLaunchKernelGGL(h1init, dim3(BATCH / 64, 512 / 64), dim3(256), 0, stream,
                       s1buf, wmat, hmat2);
    hipLaunchKernelGGL(clustering, dim3(BATCH), dim3(256), 0, stream,
                       lat, s1buf, hmat2, wmat, rep, out);
}

// Round 20
// 397.118 us; speedup vs baseline: 1.0796x; 1.0796x over previous
//
#include <hip/hip_runtime.h>
#include <hip/hip_bf16.h>
#include <math.h>

#define BATCH 1024
#define LABEL 128
#define LATENT 512
#define NTOT 1152  // 1024 + 128

typedef short short8 __attribute__((ext_vector_type(8)));
typedef float f32x16 __attribute__((ext_vector_type(16)));

__device__ __forceinline__ unsigned short f2bf(float f) {
    __hip_bfloat16 h = __float2bfloat16(f);
    return *(unsigned short*)&h;
}
__device__ __forceinline__ float bf2f(unsigned short u) {
    __hip_bfloat16 h; *(unsigned short*)&h = u;
    return __bfloat162float(h);
}

#define BSTR ((size_t)512 * 3136)
#define ASTR ((size_t)NTOT * 3136)
#define A2STR ((size_t)BATCH * 512)
#define W2STR ((size_t)LABEL * 512)

// conv1 output layout (per image): 2 bf16 planes of 6400 ushorts.
// Plane = 196 compact pixels (14x14) x 32ch, granule = 64B, slot-swizzled:
// off = p*32 + (((oc>>3) ^ (p>>1)) & 3)*8 + (oc&7).  Granules 196..199 zeroed.
//
// NUMERICS RULE (r15): w_kernel/rho keep r14-exact op order (Hopfield sign
// cascades). COVERAGE RULE (r16): conv1 writes all 196 pixels (xh loop).
// r19 lesson: k=1 hoist into GEMMs regressed (+28us) -- clustering's flip
// burst is already latency-hidden; do not add kernels to the tail.

// ------- conv1 v3 (r17 proven) ------------------------------------------------
__global__ __launch_bounds__(256) void conv1_pool(const float* __restrict__ image,
                                                  const float* __restrict__ limg,
                                                  const float* __restrict__ wt,
                                                  const float* __restrict__ bias,
                                                  unsigned short* __restrict__ o1b) {
    const int n = blockIdx.x;
    const float* in = (n < BATCH) ? (image + (size_t)n * 784)
                                  : (limg + (size_t)(n - BATCH) * 784);
    __shared__ float pin[32][32];
    __shared__ float wts[32 * 25];
    const int tid = threadIdx.x;
    unsigned short* ob = o1b + (size_t)n * 12800;
    for (int i = tid; i < 256; i += 256) {
        int pl_ = i >> 7, r = i & 127;
        ob[pl_ * 6400 + 6272 + r] = 0;
    }
    for (int idx = tid; idx < 32 * 32; idx += 256) ((float*)pin)[idx] = 0.f;
    __syncthreads();
    for (int idx = tid; idx < 784; idx += 256) {
        int y = idx / 28, x = idx % 28;
        pin[y + 2][x + 2] = in[idx];
    }
    for (int idx = tid; idx < 800; idx += 256) wts[idx] = wt[idx];
    __syncthreads();
    const int oc = tid & 31;
    float wk[25];
    #pragma unroll
    for (int k = 0; k < 25; ++k) wk[k] = wts[oc * 25 + k];
    const float b = bias[oc];
    const int slot_lo = (oc & 7);
    const int gq = oc >> 3;
    for (int it = 0; it < 2; ++it) {
        const int py = (tid >> 5) + it * 8;
        if (py >= 14) continue;
        #pragma unroll
        for (int xh = 0; xh < 2; ++xh) {
            const int acol = xh ? 12 : 0;
            const int off = xh ? 2 : 0;
            float a0[14], a1[14];
            #pragma unroll
            for (int c = 0; c < 14; ++c) { a0[c] = b; a1[c] = b; }
            #pragma unroll
            for (int t = 0; t < 6; ++t) {
                float row[20];
                const float4* rp = (const float4*)&pin[2 * py + t][acol];
                #pragma unroll
                for (int v = 0; v < 5; ++v) {
                    float4 f = rp[v];
                    row[4 * v] = f.x; row[4 * v + 1] = f.y;
                    row[4 * v + 2] = f.z; row[4 * v + 3] = f.w;
                }
                if (t < 5) {
                    #pragma unroll
                    for (int kx = 0; kx < 5; ++kx) {
                        float w0 = wk[t * 5 + kx];
                        #pragma unroll
                        for (int c = 0; c < 14; ++c)
                            a0[c] = fmaf(row[c + kx + off], w0, a0[c]);
                    }
                }
                if (t >= 1) {
                    #pragma unroll
                    for (int kx = 0; kx < 5; ++kx) {
                        float w1 = wk[(t - 1) * 5 + kx];
                        #pragma unroll
                        for (int c = 0; c < 14; ++c)
                            a1[c] = fmaf(row[c + kx + off], w1, a1[c]);
                    }
                }
            }
            #pragma unroll
            for (int px = 0; px < 7; ++px) {
                float v = fmaxf(fmaxf(a0[2 * px], a0[2 * px + 1]),
                                fmaxf(a1[2 * px], a1[2 * px + 1]));
                v = fmaxf(v, 0.f);
                unsigned short b1 = f2bf(v);
                unsigned short b2 = f2bf(v - bf2f(b1));
                int p = py * 14 + 7 * xh + px;
                int offo = p * 32 + (((gq ^ (p >> 1)) & 3) << 3) + slot_lo;
                ob[offo] = b1; ob[6400 + offo] = b2;
            }
        }
    }
}

// ------- merged prep (r17 proven) ---------------------------------------------
__global__ __launch_bounds__(256) void prep(const float* __restrict__ c2w,
                                            const float* __restrict__ f1w,
                                            const float* __restrict__ fnw,
                                            unsigned short* __restrict__ Bf,
                                            unsigned short* __restrict__ Bw2,
                                            unsigned short* __restrict__ Bn2) {
    int idx = blockIdx.x * 256 + threadIdx.x;
    if (idx < 102400) {
        int j = idx & 7, lane = (idx >> 3) & 63, ocT = (idx >> 9) & 1, s = idx >> 10;
        int q = lane >> 5, nn = lane & 31;
        int k = 16 * s + 8 * q + j;
        int tap = k >> 5, ic = k & 31;
        int oc = 32 * ocT + nn;
        float v = c2w[oc * 800 + ic * 25 + tap];
        unsigned short b1 = f2bf(v);
        unsigned short b2 = f2bf(v - bf2f(b1));
        size_t base = ((size_t)(s * 2 + ocT) * 2) * 512 + lane * 8 + j;
        Bf[base] = b1; Bf[base + 512] = b2;
        return;
    }
    int i2 = idx - 102400;
    if (i2 < 512 * 3136) {
        float v = f1w[i2];
        unsigned short b1 = f2bf(v);
        unsigned short b2 = f2bf(v - bf2f(b1));
        Bw2[i2] = b1; Bw2[BSTR + i2] = b2;
        return;
    }
    int i3 = i2 - 512 * 3136;
    if (i3 >= 128 * 512) return;
    float v = fnw[i3];
    unsigned short b1 = f2bf(v);
    unsigned short b2 = f2bf(v - bf2f(b1));
    Bn2[i3] = b1; Bn2[W2STR + i3] = b2;
}

// ------- conv2 via MFMA, v7 (r13 proven, unchanged) ---------------------------
__global__ __launch_bounds__(256) void conv2_mfma(const unsigned short* __restrict__ o1b,
                                                  const unsigned short* __restrict__ Bf,
                                                  const float* __restrict__ bias,
                                                  unsigned short* __restrict__ out2) {
    const int n = blockIdx.x;
    __shared__ __align__(16) unsigned short pl[12800];
    const int tid = threadIdx.x;
    const int lane = tid & 63, wv = tid >> 6;
    const int ocT = wv & 1, mh = wv >> 1;

    {
        const float4* src = (const float4*)(o1b + (size_t)n * 12800);
        float4* dst = (float4*)pl;
        for (int i = tid; i < 1600; i += 256) dst[i] = src[i];
    }
    __syncthreads();

    const int m_ = lane & 31, q = lane >> 5;
    int ym[4], xm[4], mm[4], tvv[4];
    #pragma unroll
    for (int tt = 0; tt < 4; ++tt) {
        int t = 4 * mh + tt;
        tvv[tt] = (t < 7);
        int m = 32 * t + m_;
        mm[tt] = m;
        ym[tt] = m / 14;
        xm[tt] = m - 14 * ym[tt];
    }
    f32x16 acc[4];
    {
        float bs = bias[32 * ocT + m_];
        #pragma unroll
        for (int tt = 0; tt < 4; ++tt)
        #pragma unroll
        for (int r = 0; r < 16; ++r) acc[tt][r] = bs;
    }

    for (int s = 0; s < 50; ++s) {
        const unsigned short* bp = Bf + ((size_t)(s * 2 + ocT) * 2) * 512 + lane * 8;
        short8 b1 = *(const short8*)(bp);
        short8 b2 = *(const short8*)(bp + 512);
        int kb = 16 * s + 8 * q;
        int tap = kb >> 5, ic0 = kb & 31, g = ic0 >> 3;
        int ky = (tap * 13) >> 6;
        int kx = tap - ky * 5;
        int iyk = ky - 2, ixk = kx - 2;
        int pq2 = iyk * 14 + ixk;
        short8 a1[4], a2[4];
        #pragma unroll
        for (int tt = 0; tt < 4; ++tt) {
            int iy = ym[tt] + iyk, ix = xm[tt] + ixk;
            int valid = tvv[tt] & ((unsigned)iy < 14u) & ((unsigned)ix < 14u);
            int cpt = valid ? (mm[tt] + pq2) : 196;
            int addr = cpt * 32 + (((g ^ (cpt >> 1)) & 3) << 3);
            a1[tt] = *(const short8*)(pl + addr);
            a2[tt] = *(const short8*)(pl + 6400 + addr);
        }
        #pragma unroll
        for (int tt = 0; tt < 4; ++tt)
            acc[tt] = __builtin_amdgcn_mfma_f32_32x32x16_bf16(a1[tt], b1, acc[tt], 0, 0, 0);
        #pragma unroll
        for (int tt = 0; tt < 4; ++tt)
            acc[tt] = __builtin_amdgcn_mfma_f32_32x32x16_bf16(a1[tt], b2, acc[tt], 0, 0, 0);
        #pragma unroll
        for (int tt = 0; tt < 4; ++tt)
            acc[tt] = __builtin_amdgcn_mfma_f32_32x32x16_bf16(a2[tt], b1, acc[tt], 0, 0, 0);
    }
    __syncthreads();

    float* hx = (float*)pl;
    {
        const int oc = 32 * ocT + m_;
        #pragma unroll
        for (int tt = 0; tt < 4; ++tt)
        #pragma unroll
        for (int e = 0; e < 8; ++e) {
            const int reg = 2 * e;
            const int r = (reg & 3) + 8 * (reg >> 2) + 4 * q;
            const int m = 32 * (4 * mh + tt) + r;
            if (m < 196) {
                float xm2 = fmaxf(acc[tt][reg], acc[tt][reg + 1]);
                int y = (m * 2341) >> 15;
                int px = (m - 14 * y) >> 1;
                hx[(y * 7 + px) * 65 + oc] = xm2;
            }
        }
    }
    __syncthreads();

    for (int idx = tid; idx < 3136; idx += 256) {
        int oc2 = (idx * 2675) >> 17;
        int p = idx - 49 * oc2;
        int py = (p * 9363) >> 16;
        int px = p - 7 * py;
        float v = fmaxf(hx[(2 * py * 7 + px) * 65 + oc2],
                        hx[((2 * py + 1) * 7 + px) * 65 + oc2]);
        v = fmaxf(v, 0.f);
        unsigned short b1 = f2bf(v);
        unsigned short b2 = f2bf(v - bf2f(b1));
        size_t o = (size_t)n * 3136 + idx;
        out2[o] = b1; out2[ASTR + o] = b2;
    }
}

// ------- fc1 via MFMA (r14 proven) --------------------------------------------
__global__ __launch_bounds__(256) void fc1_mfma(const unsigned short* __restrict__ A2,
                                                const unsigned short* __restrict__ B2,
                                                float* __restrict__ part) {
    __shared__ unsigned short As[2][2048];
    __shared__ unsigned short Bs[2][2048];
    const int tid = threadIdx.x;
    const int n0 = blockIdx.x * 64, m0 = blockIdx.y * 64;
    const int koff = blockIdx.z * 448;
    const int lr = tid >> 2, g = tid & 3;
    const int slot = (((g ^ (lr >> 1)) & 3) << 3);
    const int lane = tid & 63, wv = tid >> 6;
    const int nq = wv & 1, mq = wv >> 1;
    const int q = lane >> 5, l31 = lane & 31;
    const int rA = 32 * nq + l31, rB = 32 * mq + l31;
    f32x16 acc;
    #pragma unroll
    for (int r = 0; r < 16; ++r) acc[r] = 0.f;

    for (int bk = 0; bk < 448; bk += 32) {
        const size_t ka = (size_t)(koff + bk + (g << 3));
        short8 av[2], bv[2];
        #pragma unroll
        for (int p = 0; p < 2; ++p) {
            av[p] = *(const short8*)(A2 + p * ASTR + (size_t)(n0 + lr) * 3136 + ka);
            bv[p] = *(const short8*)(B2 + p * BSTR + (size_t)(m0 + lr) * 3136 + ka);
        }
        __syncthreads();
        #pragma unroll
        for (int p = 0; p < 2; ++p) {
            *(short8*)&As[p][(lr << 5) + slot] = av[p];
            *(short8*)&Bs[p][(lr << 5) + slot] = bv[p];
        }
        __syncthreads();
        #pragma unroll
        for (int s2 = 0; s2 < 32; s2 += 16) {
            const int gg = (s2 + (q << 3)) >> 3;
            const int sa = (((gg ^ (rA >> 1)) & 3) << 3);
            const int sb = (((gg ^ (rB >> 1)) & 3) << 3);
            short8 a1 = *(const short8*)&As[0][(rA << 5) + sa];
            short8 a2 = *(const short8*)&As[1][(rA << 5) + sa];
            short8 b1 = *(const short8*)&Bs[0][(rB << 5) + sb];
            short8 b2 = *(const short8*)&Bs[1][(rB << 5) + sb];
            acc = __builtin_amdgcn_mfma_f32_32x32x16_bf16(a1, b1, acc, 0, 0, 0);
            acc = __builtin_amdgcn_mfma_f32_32x32x16_bf16(a1, b2, acc, 0, 0, 0);
            acc = __builtin_amdgcn_mfma_f32_32x32x16_bf16(a2, b1, acc, 0, 0, 0);
        }
    }
    float* pb = part + (size_t)blockIdx.z * NTOT * 512;
    #pragma unroll
    for (int reg = 0; reg < 16; ++reg) {
        int nn = n0 + 32 * nq + (reg & 3) + 8 * (reg >> 2) + 4 * q;
        int mmo = m0 + 32 * mq + l31;
        pb[(size_t)nn * 512 + mmo] = acc[reg];
    }
}

__global__ __launch_bounds__(256) void fc1_reduce(const float* __restrict__ part,
                                                  const float* __restrict__ bias,
                                                  float* __restrict__ lat,
                                                  unsigned short* __restrict__ lat2,
                                                  float* __restrict__ rep) {
    int idx = blockIdx.x * 256 + threadIdx.x;
    int m = idx & 511;
    float v = bias[m];
    #pragma unroll
    for (int kz = 0; kz < 7; ++kz) v += part[(size_t)kz * NTOT * 512 + idx];
    if (idx < BATCH * 512) {
        lat[idx] = v;
        unsigned short b1 = f2bf(v);
        lat2[idx] = b1;
        lat2[A2STR + idx] = f2bf(v - bf2f(b1));
    } else {
        rep[idx - BATCH * 512] = tanhf(v);
    }
}

// ------- fcn logits via MFMA (r17 proven) -------------------------------------
__global__ __launch_bounds__(256) void fcn_mfma(const unsigned short* __restrict__ A2,
                                                const unsigned short* __restrict__ B2,
                                                float* __restrict__ logits) {
    __shared__ unsigned short As[2][2048];
    __shared__ unsigned short Bs[2][2048];
    const int tid = threadIdx.x;
    const int n0 = blockIdx.x * 64, m0 = blockIdx.y * 64;
    const int lr = tid >> 2, g = tid & 3;
    const int slot = (((g ^ (lr >> 1)) & 3) << 3);
    const int lane = tid & 63, wv = tid >> 6;
    const int nq = wv & 1, mq = wv >> 1;
    const int q = lane >> 5, l31 = lane & 31;
    const int rA = 32 * nq + l31, rB = 32 * mq + l31;
    f32x16 acc;
    #pragma unroll
    for (int r = 0; r < 16; ++r) acc[r] = 0.f;

    for (int bk = 0; bk < 512; bk += 32) {
        const size_t ka = (size_t)(bk + (g << 3));
        short8 av[2], bv[2];
        #pragma unroll
        for (int p = 0; p < 2; ++p) {
            av[p] = *(const short8*)(A2 + p * A2STR + (size_t)(n0 + lr) * 512 + ka);
            bv[p] = *(const short8*)(B2 + p * W2STR + (size_t)(m0 + lr) * 512 + ka);
        }
        __syncthreads();
        #pragma unroll
        for (int p = 0; p < 2; ++p) {
            *(short8*)&As[p][(lr << 5) + slot] = av[p];
            *(short8*)&Bs[p][(lr << 5) + slot] = bv[p];
        }
        __syncthreads();
        #pragma unroll
        for (int s2 = 0; s2 < 32; s2 += 16) {
            const int gg = (s2 + (q << 3)) >> 3;
            const int sa = (((gg ^ (rA >> 1)) & 3) << 3);
            const int sb = (((gg ^ (rB >> 1)) & 3) << 3);
            short8 a1 = *(const short8*)&As[0][(rA << 5) + sa];
            short8 a2 = *(const short8*)&As[1][(rA << 5) + sa];
            short8 b1 = *(const short8*)&Bs[0][(rB << 5) + sb];
            short8 b2 = *(const short8*)&Bs[1][(rB << 5) + sb];
            acc = __builtin_amdgcn_mfma_f32_32x32x16_bf16(a1, b1, acc, 0, 0, 0);
            acc = __builtin_amdgcn_mfma_f32_32x32x16_bf16(a1, b2, acc, 0, 0, 0);
            acc = __builtin_amdgcn_mfma_f32_32x32x16_bf16(a2, b1, acc, 0, 0, 0);
        }
    }
    #pragma unroll
    for (int reg = 0; reg < 16; ++reg) {
        int nn = n0 + 32 * nq + (reg & 3) + 8 * (reg >> 2) + 4 * q;
        int mmo = m0 + 32 * mq + l31;
        logits[(size_t)nn * 128 + mmo] = acc[reg];
    }
}

__global__ __launch_bounds__(128) void fcn_softmax2(const float* __restrict__ logits,
                                                    const float* __restrict__ fb,
                                                    float* __restrict__ out) {
    const int b = blockIdx.x;
    const int j = threadIdx.x;
    __shared__ float red[128];
    float acc = logits[(size_t)b * 128 + j] + fb[j];
    red[j] = acc;
    __syncthreads();
    for (int off = 64; off >= 1; off >>= 1) {
        if (j < off) red[j] = fmaxf(red[j], red[j + off]);
        __syncthreads();
    }
    float mx = red[0];
    __syncthreads();
    float ex = expf(acc - mx);
    red[j] = ex;
    __syncthreads();
    for (int off = 64; off >= 1; off >>= 1) {
        if (j < off) red[j] += red[j + off];
        __syncthreads();
    }
    out[(size_t)b * 128 + j] = ex / red[0];
}

// ------- rho (r14-exact, numerics load-bearing) -------------------------------
__global__ __launch_bounds__(256) void rho_kernel(const float* __restrict__ rep,
                                                  float* __restrict__ rho) {
    __shared__ float red[256];
    const int tid = threadIdx.x;
    float s = 0.f;
    for (int i = tid; i < LABEL * LATENT; i += 256) s += rep[i];
    red[tid] = s;
    __syncthreads();
    for (int off = 128; off >= 1; off >>= 1) {
        if (tid < off) red[tid] += red[tid + off];
        __syncthreads();
    }
    if (tid == 0) rho[0] = red[0] / (float)(LABEL * LATENT);
}

// ------- t v2 (r18 proven, elementwise transpose) -----------------------------
__global__ __launch_bounds__(256) void t_kernel(const float* __restrict__ rep,
                                                const float* __restrict__ rho,
                                                float* __restrict__ tT) {
    __shared__ float tile[64][65];
    const int tid = threadIdx.x;
    const int i0 = blockIdx.x * 64, k0 = blockIdx.y * 64;
    const int tx = tid & 63, ty4 = tid >> 6;
    const float r0 = rho[0];
    #pragma unroll
    for (int rr = 0; rr < 16; ++rr) {
        int kk = ty4 * 16 + rr;
        tile[kk][tx] = rep[(size_t)(k0 + kk) * 512 + i0 + tx];
    }
    __syncthreads();
    #pragma unroll
    for (int rr = 0; rr < 16; ++rr) {
        int ii = ty4 * 16 + rr;
        tT[(size_t)(i0 + ii) * 128 + k0 + tx] = tile[tx][ii] - r0;
    }
}

// ------- w_kernel: r14-EXACT (summation order load-bearing) -------------------
__global__ __launch_bounds__(256) void w_kernel(const float* __restrict__ tT,
                                                float* __restrict__ w) {
    int idx = blockIdx.x * 256 + threadIdx.x;
    int i = idx >> 9, j = idx & 511;
    const float4* a = (const float4*)(tT + i * 128);
    const float4* b = (const float4*)(tT + j * 128);
    float acc = 0.f;
    #pragma unroll 8
    for (int q = 0; q < 32; ++q) {
        float4 av = a[q], bv = b[q];
        acc += av.x * bv.x + av.y * bv.y + av.z * bv.z + av.w * bv.w;
    }
    w[idx] = (i == j) ? 0.f : acc * (1.f / 128.f);
}

// ------- hinit (r14 proven) ---------------------------------------------------
__global__ __launch_bounds__(256) void hinit(const float* __restrict__ lat,
                                             const float* __restrict__ w,
                                             float* __restrict__ hmat) {
    __shared__ float As[16][68];
    __shared__ float Bs[16][68];
    const int tid = threadIdx.x;
    const int n0 = blockIdx.x * 64, m0 = blockIdx.y * 64;
    const int lr = tid >> 2;
    const int lk = (tid & 3) * 4;
    const int ty = tid >> 4, tx = tid & 15;
    float c[4][4] = {};
    for (int k0 = 0; k0 < 512; k0 += 16) {
        float4 a4 = *(const float4*)(lat + (size_t)(n0 + lr) * 512 + k0 + lk);
        float4 b4 = *(const float4*)(w + (size_t)(m0 + lr) * 512 + k0 + lk);
        a4.x = tanhf(a4.x); a4.y = tanhf(a4.y); a4.z = tanhf(a4.z); a4.w = tanhf(a4.w);
        __syncthreads();
        As[lk + 0][lr] = a4.x; As[lk + 1][lr] = a4.y; As[lk + 2][lr] = a4.z; As[lk + 3][lr] = a4.w;
        Bs[lk + 0][lr] = b4.x; Bs[lk + 1][lr] = b4.y; Bs[lk + 2][lr] = b4.z; Bs[lk + 3][lr] = b4.w;
        __syncthreads();
        #pragma unroll
        for (int kk = 0; kk < 16; ++kk) {
            float av[4], bv[4];
            #pragma unroll
            for (int i = 0; i < 4; ++i) av[i] = As[kk][ty * 4 + i];
            #pragma unroll
            for (int j = 0; j < 4; ++j) bv[j] = Bs[kk][tx * 4 + j];
            #pragma unroll
            for (int i = 0; i < 4; ++i)
            #pragma unroll
            for (int j = 0; j < 4; ++j) c[i][j] += av[i] * bv[j];
        }
    }
    #pragma unroll
    for (int i = 0; i < 4; ++i)
    #pragma unroll
    for (int j = 0; j < 4; ++j)
        hmat[(size_t)(n0 + ty * 4 + i) * 512 + m0 + tx * 4 + j] = c[i][j];
}

// ------- clustering v3 (r18 proven): CB=1, incremental Hopfield ---------------
__device__ __forceinline__ float sgnf(float x) {
    return (x > 0.f) ? 1.f : ((x < 0.f) ? -1.f : 0.f);
}

__global__ __launch_bounds__(256) void clustering(const float* __restrict__ lat,
                                                  const float* __restrict__ hmat,
                                                  const float* __restrict__ w,
                                                  const float* __restrict__ rep,
                                                  float* __restrict__ out) {
    const int tid = threadIdx.x;
    const int row = blockIdx.x;
    __shared__ float mins[512];
    __shared__ float red[256];
    __shared__ float part_e[4];
    __shared__ int part_c[4];
    __shared__ float min_e_s;
    __shared__ int copyf_s;
    __shared__ int donef_s;
    __shared__ int cnt_s;
    __shared__ int jidx[512];
    __shared__ float jdel[512];
    const int i0 = 2 * tid, i1 = 2 * tid + 1;
    const int wave = tid >> 6, lane = tid & 63;

    float sm10, sm11, sm20, sm21, h0, h1;
    {
        sm10 = tanhf(lat[(size_t)row * 512 + i0]);
        sm11 = tanhf(lat[(size_t)row * 512 + i1]);
        sm20 = sm10; sm21 = sm11;
        h0 = hmat[(size_t)row * 512 + i0];
        h1 = hmat[(size_t)row * 512 + i1];
    }
    if (tid == 0) { min_e_s = INFINITY; donef_s = 0; cnt_s = 0; }
    __syncthreads();

    for (int k = 1; k <= 512; ++k) {
        float sn0 = fabsf(sm10) * sgnf(h0);
        float sn1 = fabsf(sm11) * sgnf(h1);
        int cy = (sn0 == sm20 && sn1 == sm21) ? 1 : 0;
        if (sn0 != sm10) {
            int p = atomicAdd(&cnt_s, 1);
            jidx[p] = i0; jdel[p] = sn0 - sm10;
        }
        if (sn1 != sm11) {
            int p = atomicAdd(&cnt_s, 1);
            jidx[p] = i1; jdel[p] = sn1 - sm11;
        }
        #pragma unroll
        for (int m = 32; m >= 1; m >>= 1) cy &= __shfl_xor(cy, m, 64);
        if (lane == 0) part_c[wave] = cy;
        __syncthreads();   // flip list complete

        {
            const int c = cnt_s;
            #pragma unroll 8
            for (int t = 0; t < c; ++t) {
                const int j = jidx[t];
                const float d = jdel[t];
                const float2 wvv = *(const float2*)(w + (size_t)j * 512 + i0);
                h0 = fmaf(d, wvv.x, h0);
                h1 = fmaf(d, wvv.y, h1);
            }
        }
        float ep = sn0 * h0 + sn1 * h1;
        #pragma unroll
        for (int m = 32; m >= 1; m >>= 1) ep += __shfl_xor(ep, m, 64);
        if (lane == 0) part_e[wave] = ep;
        __syncthreads();

        if (tid == 0) {
            float e = -(part_e[0] + part_e[1] + part_e[2] + part_e[3]);
            int better = e < min_e_s;
            if (better) min_e_s = e;
            copyf_s = better;
            int fl = part_c[0] & part_c[1] & part_c[2] & part_c[3];
            int fixedp = (cnt_s == 0);
            int cyc = (k >= 2) && fl;
            if (fixedp || cyc) donef_s = 1;
            cnt_s = 0;
        }
        __syncthreads();

        if (copyf_s) { mins[i0] = sn0; mins[i1] = sn1; }
        sm20 = sm10; sm21 = sm11;
        sm10 = sn0;  sm11 = sn1;
        if (donef_s) break;
    }
    __syncthreads();

    const int j = tid & 127, half = tid >> 7;
    {
        const float4* rr = (const float4*)(rep + (size_t)j * 512 + half * 256);
        const float4* ms = (const float4*)(&mins[half * 256]);
        float p = 0.f;
        #pragma unroll 8
        for (int q = 0; q < 64; ++q) {
            float4 rv = rr[q], mv = ms[q];
            p += rv.x * mv.x + rv.y * mv.y + rv.z * mv.z + rv.w * mv.w;
        }
        red[tid] = p;
        __syncthreads();
        float v = 0.f;
        if (tid < 128) { v = fabsf(red[tid] + red[tid + 128]); red[tid] = v; }
        __syncthreads();
        for (int off = 64; off >= 1; off >>= 1) {
            if (tid < off) red[tid] = fmaxf(red[tid], red[tid + off]);
            __syncthreads();
        }
        float mx = red[0];
        __syncthreads();
        float ex = 0.f;
        if (tid < 128) { ex = expf(v - mx); red[tid] = ex; }
        __syncthreads();
        for (int off = 64; off >= 1; off >>= 1) {
            if (tid < off) red[tid] += red[tid + off];
            __syncthreads();
        }
        if (tid < 128) out[(size_t)row * 128 + tid] = ex / red[0];
    }
}

extern "C" void kernel_launch(void* const* d_in, const int* in_sizes, int n_in,
                              void* d_out, int out_size, void* d_ws, size_t ws_size,
                              hipStream_t stream) {
    const float* image = (const float*)d_in[0];
    const float* limg  = (const float*)d_in[1];
    const float* c1w   = (const float*)d_in[2];
    const float* c1b   = (const float*)d_in[3];
    const float* c2w   = (const float*)d_in[4];
    const float* c2b   = (const float*)d_in[5];
    const float* f1w   = (const float*)d_in[6];
    const float* f1b   = (const float*)d_in[7];
    const float* fnw   = (const float*)d_in[8];
    const float* fnb   = (const float*)d_in[9];
    float* out = (float*)d_out;
    float* ws  = (float*)d_ws;

    unsigned short* o1b  = (unsigned short*)ws;        // 1152*12800 us
    unsigned short* out2 = o1b + (size_t)NTOT * 12800; // 2*ASTR bf16
    float* lat  = (float*)(out2 + 2 * ASTR);           // 1024*512
    float* rep  = lat + (size_t)BATCH * 512;           // 128*512
    float* tT   = rep + (size_t)LABEL * 512;           // 512*128
    float* wmat = tT + (size_t)512 * 128;              // 512*512
    float* rho  = wmat + (size_t)512 * 512;            // 1 (+pad)
    unsigned short* Bw2   = (unsigned short*)(rho + 16);   // 2*BSTR bf16
    unsigned short* Bfrag = Bw2 + 2 * BSTR;                // 102,400 bf16
    float* hmat = (float*)(Bfrag + 102400);            // 1024*512 f32
    unsigned short* lat2 = (unsigned short*)(hmat + A2STR);  // 2*A2STR bf16
    unsigned short* fnw2 = lat2 + 2 * A2STR;           // 2*W2STR bf16
    float* logits = (float*)(fnw2 + 2 * W2STR);        // 1024*128 f32
    float* part = (float*)ws;                          // alias o1b (dead after conv2)

    const int prep_total = 102400 + 512 * 3136 + 128 * 512;
    hipLaunchKernelGGL(prep, dim3((prep_total + 255) / 256), dim3(256), 0, stream,
                       c2w, f1w, fnw, Bfrag, Bw2, fnw2);
    hipLaunchKernelGGL(conv1_pool, dim3(NTOT), dim3(256), 0, stream, image, limg, c1w, c1b, o1b);
    hipLaunchKernelGGL(conv2_mfma, dim3(NTOT), dim3(256), 0, stream, o1b, Bfrag, c2b, out2);
    hipLaunchKernelGGL(fc1_mfma, dim3(NTOT / 64, 512 / 64, 7), dim3(256), 0, stream,
                       out2, Bw2, part);
    hipLaunchKernelGGL(fc1_reduce, dim3(NTOT * 512 / 256), dim3(256), 0, stream,
                       part, f1b, lat, lat2, rep);
    hipLaunchKernelGGL(fcn_mfma, dim3(16, 2), dim3(256), 0, stream, lat2, fnw2, logits);
    hipLaunchKernelGGL(fcn_softmax2, dim3(BATCH), dim3(128), 0, stream, logits, fnb,
                       out + (size_t)BATCH * LABEL);
    hipLaunchKernelGGL(rho_kernel, dim3(1), dim3(256), 0, stream, rep, rho);
    hipLaunchKernelGGL(t_kernel, dim3(8, 2), dim3(256), 0, stream, rep, rho, tT);
    hipLaunchKernelGGL(w_kernel, dim3(1024), dim3(256), 0, stream, tT, wmat);
    hipLaunchKernelGGL(hinit, dim3(BATCH / 64, 512 / 64), dim3(256), 0, stream, lat, wmat, hmat);
    hipLaunchKernelGGL(clustering, dim3(BATCH), dim3(256), 0, stream,
                       lat, hmat, wmat, rep, out);
}

// Round 21
// 394.859 us; speedup vs baseline: 1.0858x; 1.0057x over previous
//
#include <hip/hip_runtime.h>
#include <hip/hip_bf16.h>
#include <math.h>

#define BATCH 1024
#define LABEL 128
#define LATENT 512
#define NTOT 1152  // 1024 + 128

typedef short short8 __attribute__((ext_vector_type(8)));
typedef float f32x16 __attribute__((ext_vector_type(16)));

__device__ __forceinline__ unsigned short f2bf(float f) {
    __hip_bfloat16 h = __float2bfloat16(f);
    return *(unsigned short*)&h;
}
__device__ __forceinline__ float bf2f(unsigned short u) {
    __hip_bfloat16 h; *(unsigned short*)&h = u;
    return __bfloat162float(h);
}

#define BSTR ((size_t)512 * 3136)
#define ASTR ((size_t)NTOT * 3136)
#define A2STR ((size_t)BATCH * 512)
#define W2STR ((size_t)LABEL * 512)

// conv1 output layout (per image): 2 bf16 planes of 6400 ushorts.
// Plane = 196 compact pixels (14x14) x 32ch, granule = 64B, slot-swizzled:
// off = p*32 + (((oc>>3) ^ (p>>1)) & 3)*8 + (oc&7).  Granules 196..199 zeroed.
//
// NUMERICS RULE (r15): w_kernel/rho keep r14-exact op order (Hopfield sign
// cascades). COVERAGE RULE (r16): conv1 writes all 196 pixels (xh loop).
// r19 lesson: do not add kernels to the tail (launch+roundtrip > savings).
// r21: conv2 dead tile (t=7) skipped via kloop<3> for mh=1 (bit-exact:
// acc[3] stays at bias, epilogue m<196 guard already discarded it).

// ------- conv1 v3 (r17 proven) ------------------------------------------------
__global__ __launch_bounds__(256) void conv1_pool(const float* __restrict__ image,
                                                  const float* __restrict__ limg,
                                                  const float* __restrict__ wt,
                                                  const float* __restrict__ bias,
                                                  unsigned short* __restrict__ o1b) {
    const int n = blockIdx.x;
    const float* in = (n < BATCH) ? (image + (size_t)n * 784)
                                  : (limg + (size_t)(n - BATCH) * 784);
    __shared__ float pin[32][32];
    __shared__ float wts[32 * 25];
    const int tid = threadIdx.x;
    unsigned short* ob = o1b + (size_t)n * 12800;
    for (int i = tid; i < 256; i += 256) {
        int pl_ = i >> 7, r = i & 127;
        ob[pl_ * 6400 + 6272 + r] = 0;
    }
    for (int idx = tid; idx < 32 * 32; idx += 256) ((float*)pin)[idx] = 0.f;
    __syncthreads();
    for (int idx = tid; idx < 784; idx += 256) {
        int y = idx / 28, x = idx % 28;
        pin[y + 2][x + 2] = in[idx];
    }
    for (int idx = tid; idx < 800; idx += 256) wts[idx] = wt[idx];
    __syncthreads();
    const int oc = tid & 31;
    float wk[25];
    #pragma unroll
    for (int k = 0; k < 25; ++k) wk[k] = wts[oc * 25 + k];
    const float b = bias[oc];
    const int slot_lo = (oc & 7);
    const int gq = oc >> 3;
    for (int it = 0; it < 2; ++it) {
        const int py = (tid >> 5) + it * 8;
        if (py >= 14) continue;
        #pragma unroll
        for (int xh = 0; xh < 2; ++xh) {
            const int acol = xh ? 12 : 0;
            const int off = xh ? 2 : 0;
            float a0[14], a1[14];
            #pragma unroll
            for (int c = 0; c < 14; ++c) { a0[c] = b; a1[c] = b; }
            #pragma unroll
            for (int t = 0; t < 6; ++t) {
                float row[20];
                const float4* rp = (const float4*)&pin[2 * py + t][acol];
                #pragma unroll
                for (int v = 0; v < 5; ++v) {
                    float4 f = rp[v];
                    row[4 * v] = f.x; row[4 * v + 1] = f.y;
                    row[4 * v + 2] = f.z; row[4 * v + 3] = f.w;
                }
                if (t < 5) {
                    #pragma unroll
                    for (int kx = 0; kx < 5; ++kx) {
                        float w0 = wk[t * 5 + kx];
                        #pragma unroll
                        for (int c = 0; c < 14; ++c)
                            a0[c] = fmaf(row[c + kx + off], w0, a0[c]);
                    }
                }
                if (t >= 1) {
                    #pragma unroll
                    for (int kx = 0; kx < 5; ++kx) {
                        float w1 = wk[(t - 1) * 5 + kx];
                        #pragma unroll
                        for (int c = 0; c < 14; ++c)
                            a1[c] = fmaf(row[c + kx + off], w1, a1[c]);
                    }
                }
            }
            #pragma unroll
            for (int px = 0; px < 7; ++px) {
                float v = fmaxf(fmaxf(a0[2 * px], a0[2 * px + 1]),
                                fmaxf(a1[2 * px], a1[2 * px + 1]));
                v = fmaxf(v, 0.f);
                unsigned short b1 = f2bf(v);
                unsigned short b2 = f2bf(v - bf2f(b1));
                int p = py * 14 + 7 * xh + px;
                int offo = p * 32 + (((gq ^ (p >> 1)) & 3) << 3) + slot_lo;
                ob[offo] = b1; ob[6400 + offo] = b2;
            }
        }
    }
}

// ------- merged prep (r17 proven) ---------------------------------------------
__global__ __launch_bounds__(256) void prep(const float* __restrict__ c2w,
                                            const float* __restrict__ f1w,
                                            const float* __restrict__ fnw,
                                            unsigned short* __restrict__ Bf,
                                            unsigned short* __restrict__ Bw2,
                                            unsigned short* __restrict__ Bn2) {
    int idx = blockIdx.x * 256 + threadIdx.x;
    if (idx < 102400) {
        int j = idx & 7, lane = (idx >> 3) & 63, ocT = (idx >> 9) & 1, s = idx >> 10;
        int q = lane >> 5, nn = lane & 31;
        int k = 16 * s + 8 * q + j;
        int tap = k >> 5, ic = k & 31;
        int oc = 32 * ocT + nn;
        float v = c2w[oc * 800 + ic * 25 + tap];
        unsigned short b1 = f2bf(v);
        unsigned short b2 = f2bf(v - bf2f(b1));
        size_t base = ((size_t)(s * 2 + ocT) * 2) * 512 + lane * 8 + j;
        Bf[base] = b1; Bf[base + 512] = b2;
        return;
    }
    int i2 = idx - 102400;
    if (i2 < 512 * 3136) {
        float v = f1w[i2];
        unsigned short b1 = f2bf(v);
        unsigned short b2 = f2bf(v - bf2f(b1));
        Bw2[i2] = b1; Bw2[BSTR + i2] = b2;
        return;
    }
    int i3 = i2 - 512 * 3136;
    if (i3 >= 128 * 512) return;
    float v = fnw[i3];
    unsigned short b1 = f2bf(v);
    unsigned short b2 = f2bf(v - bf2f(b1));
    Bn2[i3] = b1; Bn2[W2STR + i3] = b2;
}

// ------- conv2 via MFMA v8: templated K-loop skips the dead tile --------------
template<int NT>
__device__ __forceinline__ void conv2_kloop(const unsigned short* __restrict__ pl,
                                            const unsigned short* __restrict__ Bf,
                                            const int ocT, const int lane, const int q,
                                            const int* __restrict__ ym,
                                            const int* __restrict__ xm,
                                            const int* __restrict__ mm,
                                            f32x16* __restrict__ acc) {
    for (int s = 0; s < 50; ++s) {
        const unsigned short* bp = Bf + ((size_t)(s * 2 + ocT) * 2) * 512 + lane * 8;
        short8 b1 = *(const short8*)(bp);
        short8 b2 = *(const short8*)(bp + 512);
        int kb = 16 * s + 8 * q;
        int tap = kb >> 5, ic0 = kb & 31, g = ic0 >> 3;
        int ky = (tap * 13) >> 6;       // exact /5 for tap<25
        int kx = tap - ky * 5;
        int iyk = ky - 2, ixk = kx - 2;
        int pq2 = iyk * 14 + ixk;
        short8 a1[NT], a2[NT];
        #pragma unroll
        for (int tt = 0; tt < NT; ++tt) {
            int iy = ym[tt] + iyk, ix = xm[tt] + ixk;
            int valid = ((unsigned)iy < 14u) & ((unsigned)ix < 14u);
            int cpt = valid ? (mm[tt] + pq2) : 196;
            int addr = cpt * 32 + (((g ^ (cpt >> 1)) & 3) << 3);
            a1[tt] = *(const short8*)(pl + addr);
            a2[tt] = *(const short8*)(pl + 6400 + addr);
        }
        #pragma unroll
        for (int tt = 0; tt < NT; ++tt)
            acc[tt] = __builtin_amdgcn_mfma_f32_32x32x16_bf16(a1[tt], b1, acc[tt], 0, 0, 0);
        #pragma unroll
        for (int tt = 0; tt < NT; ++tt)
            acc[tt] = __builtin_amdgcn_mfma_f32_32x32x16_bf16(a1[tt], b2, acc[tt], 0, 0, 0);
        #pragma unroll
        for (int tt = 0; tt < NT; ++tt)
            acc[tt] = __builtin_amdgcn_mfma_f32_32x32x16_bf16(a2[tt], b1, acc[tt], 0, 0, 0);
    }
}

__global__ __launch_bounds__(256) void conv2_mfma(const unsigned short* __restrict__ o1b,
                                                  const unsigned short* __restrict__ Bf,
                                                  const float* __restrict__ bias,
                                                  unsigned short* __restrict__ out2) {
    const int n = blockIdx.x;
    __shared__ __align__(16) unsigned short pl[12800];
    const int tid = threadIdx.x;
    const int lane = tid & 63, wv = tid >> 6;
    const int ocT = wv & 1, mh = wv >> 1;

    {
        const float4* src = (const float4*)(o1b + (size_t)n * 12800);
        float4* dst = (float4*)pl;
        for (int i = tid; i < 1600; i += 256) dst[i] = src[i];
    }
    __syncthreads();

    const int m_ = lane & 31, q = lane >> 5;
    int ym[4], xm[4], mm[4];
    #pragma unroll
    for (int tt = 0; tt < 4; ++tt) {
        int t = 4 * mh + tt;
        if (t > 6) t = 6;               // tt=3/mh=1 dummy (never used by kloop<3>)
        int m = 32 * t + m_;
        mm[tt] = m;
        ym[tt] = m / 14;
        xm[tt] = m - 14 * ym[tt];
    }
    f32x16 acc[4];
    {
        float bs = bias[32 * ocT + m_];
        #pragma unroll
        for (int tt = 0; tt < 4; ++tt)
        #pragma unroll
        for (int r = 0; r < 16; ++r) acc[tt][r] = bs;
    }

    if (mh == 0) conv2_kloop<4>(pl, Bf, ocT, lane, q, ym, xm, mm, acc);
    else         conv2_kloop<3>(pl, Bf, ocT, lane, q, ym, xm, mm, acc);
    __syncthreads();

    float* hx = (float*)pl;
    {
        const int oc = 32 * ocT + m_;
        #pragma unroll
        for (int tt = 0; tt < 4; ++tt)
        #pragma unroll
        for (int e = 0; e < 8; ++e) {
            const int reg = 2 * e;
            const int r = (reg & 3) + 8 * (reg >> 2) + 4 * q;
            const int m = 32 * (4 * mh + tt) + r;   // mh=1,tt=3 -> m>=224: guarded out
            if (m < 196) {
                float xm2 = fmaxf(acc[tt][reg], acc[tt][reg + 1]);
                int y = (m * 2341) >> 15;
                int px = (m - 14 * y) >> 1;
                hx[(y * 7 + px) * 65 + oc] = xm2;
            }
        }
    }
    __syncthreads();

    for (int idx = tid; idx < 3136; idx += 256) {
        int oc2 = (idx * 2675) >> 17;
        int p = idx - 49 * oc2;
        int py = (p * 9363) >> 16;
        int px = p - 7 * py;
        float v = fmaxf(hx[(2 * py * 7 + px) * 65 + oc2],
                        hx[((2 * py + 1) * 7 + px) * 65 + oc2]);
        v = fmaxf(v, 0.f);
        unsigned short b1 = f2bf(v);
        unsigned short b2 = f2bf(v - bf2f(b1));
        size_t o = (size_t)n * 3136 + idx;
        out2[o] = b1; out2[ASTR + o] = b2;
    }
}

// ------- fc1 via MFMA (r14 proven) --------------------------------------------
__global__ __launch_bounds__(256) void fc1_mfma(const unsigned short* __restrict__ A2,
                                                const unsigned short* __restrict__ B2,
                                                float* __restrict__ part) {
    __shared__ unsigned short As[2][2048];
    __shared__ unsigned short Bs[2][2048];
    const int tid = threadIdx.x;
    const int n0 = blockIdx.x * 64, m0 = blockIdx.y * 64;
    const int koff = blockIdx.z * 448;
    const int lr = tid >> 2, g = tid & 3;
    const int slot = (((g ^ (lr >> 1)) & 3) << 3);
    const int lane = tid & 63, wv = tid >> 6;
    const int nq = wv & 1, mq = wv >> 1;
    const int q = lane >> 5, l31 = lane & 31;
    const int rA = 32 * nq + l31, rB = 32 * mq + l31;
    f32x16 acc;
    #pragma unroll
    for (int r = 0; r < 16; ++r) acc[r] = 0.f;

    for (int bk = 0; bk < 448; bk += 32) {
        const size_t ka = (size_t)(koff + bk + (g << 3));
        short8 av[2], bv[2];
        #pragma unroll
        for (int p = 0; p < 2; ++p) {
            av[p] = *(const short8*)(A2 + p * ASTR + (size_t)(n0 + lr) * 3136 + ka);
            bv[p] = *(const short8*)(B2 + p * BSTR + (size_t)(m0 + lr) * 3136 + ka);
        }
        __syncthreads();
        #pragma unroll
        for (int p = 0; p < 2; ++p) {
            *(short8*)&As[p][(lr << 5) + slot] = av[p];
            *(short8*)&Bs[p][(lr << 5) + slot] = bv[p];
        }
        __syncthreads();
        #pragma unroll
        for (int s2 = 0; s2 < 32; s2 += 16) {
            const int gg = (s2 + (q << 3)) >> 3;
            const int sa = (((gg ^ (rA >> 1)) & 3) << 3);
            const int sb = (((gg ^ (rB >> 1)) & 3) << 3);
            short8 a1 = *(const short8*)&As[0][(rA << 5) + sa];
            short8 a2 = *(const short8*)&As[1][(rA << 5) + sa];
            short8 b1 = *(const short8*)&Bs[0][(rB << 5) + sb];
            short8 b2 = *(const short8*)&Bs[1][(rB << 5) + sb];
            acc = __builtin_amdgcn_mfma_f32_32x32x16_bf16(a1, b1, acc, 0, 0, 0);
            acc = __builtin_amdgcn_mfma_f32_32x32x16_bf16(a1, b2, acc, 0, 0, 0);
            acc = __builtin_amdgcn_mfma_f32_32x32x16_bf16(a2, b1, acc, 0, 0, 0);
        }
    }
    float* pb = part + (size_t)blockIdx.z * NTOT * 512;
    #pragma unroll
    for (int reg = 0; reg < 16; ++reg) {
        int nn = n0 + 32 * nq + (reg & 3) + 8 * (reg >> 2) + 4 * q;
        int mmo = m0 + 32 * mq + l31;
        pb[(size_t)nn * 512 + mmo] = acc[reg];
    }
}

__global__ __launch_bounds__(256) void fc1_reduce(const float* __restrict__ part,
                                                  const float* __restrict__ bias,
                                                  float* __restrict__ lat,
                                                  unsigned short* __restrict__ lat2,
                                                  float* __restrict__ rep) {
    int idx = blockIdx.x * 256 + threadIdx.x;
    int m = idx & 511;
    float v = bias[m];
    #pragma unroll
    for (int kz = 0; kz < 7; ++kz) v += part[(size_t)kz * NTOT * 512 + idx];
    if (idx < BATCH * 512) {
        lat[idx] = v;
        unsigned short b1 = f2bf(v);
        lat2[idx] = b1;
        lat2[A2STR + idx] = f2bf(v - bf2f(b1));
    } else {
        rep[idx - BATCH * 512] = tanhf(v);
    }
}

// ------- fcn logits via MFMA (r17 proven) -------------------------------------
__global__ __launch_bounds__(256) void fcn_mfma(const unsigned short* __restrict__ A2,
                                                const unsigned short* __restrict__ B2,
                                                float* __restrict__ logits) {
    __shared__ unsigned short As[2][2048];
    __shared__ unsigned short Bs[2][2048];
    const int tid = threadIdx.x;
    const int n0 = blockIdx.x * 64, m0 = blockIdx.y * 64;
    const int lr = tid >> 2, g = tid & 3;
    const int slot = (((g ^ (lr >> 1)) & 3) << 3);
    const int lane = tid & 63, wv = tid >> 6;
    const int nq = wv & 1, mq = wv >> 1;
    const int q = lane >> 5, l31 = lane & 31;
    const int rA = 32 * nq + l31, rB = 32 * mq + l31;
    f32x16 acc;
    #pragma unroll
    for (int r = 0; r < 16; ++r) acc[r] = 0.f;

    for (int bk = 0; bk < 512; bk += 32) {
        const size_t ka = (size_t)(bk + (g << 3));
        short8 av[2], bv[2];
        #pragma unroll
        for (int p = 0; p < 2; ++p) {
            av[p] = *(const short8*)(A2 + p * A2STR + (size_t)(n0 + lr) * 512 + ka);
            bv[p] = *(const short8*)(B2 + p * W2STR + (size_t)(m0 + lr) * 512 + ka);
        }
        __syncthreads();
        #pragma unroll
        for (int p = 0; p < 2; ++p) {
            *(short8*)&As[p][(lr << 5) + slot] = av[p];
            *(short8*)&Bs[p][(lr << 5) + slot] = bv[p];
        }
        __syncthreads();
        #pragma unroll
        for (int s2 = 0; s2 < 32; s2 += 16) {
            const int gg = (s2 + (q << 3)) >> 3;
            const int sa = (((gg ^ (rA >> 1)) & 3) << 3);
            const int sb = (((gg ^ (rB >> 1)) & 3) << 3);
            short8 a1 = *(const short8*)&As[0][(rA << 5) + sa];
            short8 a2 = *(const short8*)&As[1][(rA << 5) + sa];
            short8 b1 = *(const short8*)&Bs[0][(rB << 5) + sb];
            short8 b2 = *(const short8*)&Bs[1][(rB << 5) + sb];
            acc = __builtin_amdgcn_mfma_f32_32x32x16_bf16(a1, b1, acc, 0, 0, 0);
            acc = __builtin_amdgcn_mfma_f32_32x32x16_bf16(a1, b2, acc, 0, 0, 0);
            acc = __builtin_amdgcn_mfma_f32_32x32x16_bf16(a2, b1, acc, 0, 0, 0);
        }
    }
    #pragma unroll
    for (int reg = 0; reg < 16; ++reg) {
        int nn = n0 + 32 * nq + (reg & 3) + 8 * (reg >> 2) + 4 * q;
        int mmo = m0 + 32 * mq + l31;
        logits[(size_t)nn * 128 + mmo] = acc[reg];
    }
}

__global__ __launch_bounds__(128) void fcn_softmax2(const float* __restrict__ logits,
                                                    const float* __restrict__ fb,
                                                    float* __restrict__ out) {
    const int b = blockIdx.x;
    const int j = threadIdx.x;
    __shared__ float red[128];
    float acc = logits[(size_t)b * 128 + j] + fb[j];
    red[j] = acc;
    __syncthreads();
    for (int off = 64; off >= 1; off >>= 1) {
        if (j < off) red[j] = fmaxf(red[j], red[j + off]);
        __syncthreads();
    }
    float mx = red[0];
    __syncthreads();
    float ex = expf(acc - mx);
    red[j] = ex;
    __syncthreads();
    for (int off = 64; off >= 1; off >>= 1) {
        if (j < off) red[j] += red[j + off];
        __syncthreads();
    }
    out[(size_t)b * 128 + j] = ex / red[0];
}

// ------- rho (r14-exact, numerics load-bearing) -------------------------------
__global__ __launch_bounds__(256) void rho_kernel(const float* __restrict__ rep,
                                                  float* __restrict__ rho) {
    __shared__ float red[256];
    const int tid = threadIdx.x;
    float s = 0.f;
    for (int i = tid; i < LABEL * LATENT; i += 256) s += rep[i];
    red[tid] = s;
    __syncthreads();
    for (int off = 128; off >= 1; off >>= 1) {
        if (tid < off) red[tid] += red[tid + off];
        __syncthreads();
    }
    if (tid == 0) rho[0] = red[0] / (float)(LABEL * LATENT);
}

// ------- t v2 (r18 proven, elementwise transpose) -----------------------------
__global__ __launch_bounds__(256) void t_kernel(const float* __restrict__ rep,
                                                const float* __restrict__ rho,
                                                float* __restrict__ tT) {
    __shared__ float tile[64][65];
    const int tid = threadIdx.x;
    const int i0 = blockIdx.x * 64, k0 = blockIdx.y * 64;
    const int tx = tid & 63, ty4 = tid >> 6;
    const float r0 = rho[0];
    #pragma unroll
    for (int rr = 0; rr < 16; ++rr) {
        int kk = ty4 * 16 + rr;
        tile[kk][tx] = rep[(size_t)(k0 + kk) * 512 + i0 + tx];
    }
    __syncthreads();
    #pragma unroll
    for (int rr = 0; rr < 16; ++rr) {
        int ii = ty4 * 16 + rr;
        tT[(size_t)(i0 + ii) * 128 + k0 + tx] = tile[tx][ii] - r0;
    }
}

// ------- w_kernel: r14-EXACT (summation order load-bearing) -------------------
__global__ __launch_bounds__(256) void w_kernel(const float* __restrict__ tT,
                                                float* __restrict__ w) {
    int idx = blockIdx.x * 256 + threadIdx.x;
    int i = idx >> 9, j = idx & 511;
    const float4* a = (const float4*)(tT + i * 128);
    const float4* b = (const float4*)(tT + j * 128);
    float acc = 0.f;
    #pragma unroll 8
    for (int q = 0; q < 32; ++q) {
        float4 av = a[q], bv = b[q];
        acc += av.x * bv.x + av.y * bv.y + av.z * bv.z + av.w * bv.w;
    }
    w[idx] = (i == j) ? 0.f : acc * (1.f / 128.f);
}

// ------- hinit (r14 proven) ---------------------------------------------------
__global__ __launch_bounds__(256) void hinit(const float* __restrict__ lat,
                                             const float* __restrict__ w,
                                             float* __restrict__ hmat) {
    __shared__ float As[16][68];
    __shared__ float Bs[16][68];
    const int tid = threadIdx.x;
    const int n0 = blockIdx.x * 64, m0 = blockIdx.y * 64;
    const int lr = tid >> 2;
    const int lk = (tid & 3) * 4;
    const int ty = tid >> 4, tx = tid & 15;
    float c[4][4] = {};
    for (int k0 = 0; k0 < 512; k0 += 16) {
        float4 a4 = *(const float4*)(lat + (size_t)(n0 + lr) * 512 + k0 + lk);
        float4 b4 = *(const float4*)(w + (size_t)(m0 + lr) * 512 + k0 + lk);
        a4.x = tanhf(a4.x); a4.y = tanhf(a4.y); a4.z = tanhf(a4.z); a4.w = tanhf(a4.w);
        __syncthreads();
        As[lk + 0][lr] = a4.x; As[lk + 1][lr] = a4.y; As[lk + 2][lr] = a4.z; As[lk + 3][lr] = a4.w;
        Bs[lk + 0][lr] = b4.x; Bs[lk + 1][lr] = b4.y; Bs[lk + 2][lr] = b4.z; Bs[lk + 3][lr] = b4.w;
        __syncthreads();
        #pragma unroll
        for (int kk = 0; kk < 16; ++kk) {
            float av[4], bv[4];
            #pragma unroll
            for (int i = 0; i < 4; ++i) av[i] = As[kk][ty * 4 + i];
            #pragma unroll
            for (int j = 0; j < 4; ++j) bv[j] = Bs[kk][tx * 4 + j];
            #pragma unroll
            for (int i = 0; i < 4; ++i)
            #pragma unroll
            for (int j = 0; j < 4; ++j) c[i][j] += av[i] * bv[j];
        }
    }
    #pragma unroll
    for (int i = 0; i < 4; ++i)
    #pragma unroll
    for (int j = 0; j < 4; ++j)
        hmat[(size_t)(n0 + ty * 4 + i) * 512 + m0 + tx * 4 + j] = c[i][j];
}

// ------- clustering v3 (r18 proven): CB=1, incremental Hopfield ---------------
__device__ __forceinline__ float sgnf(float x) {
    return (x > 0.f) ? 1.f : ((x < 0.f) ? -1.f : 0.f);
}

__global__ __launch_bounds__(256) void clustering(const float* __restrict__ lat,
                                                  const float* __restrict__ hmat,
                                                  const float* __restrict__ w,
                                                  const float* __restrict__ rep,
                                                  float* __restrict__ out) {
    const int tid = threadIdx.x;
    const int row = blockIdx.x;
    __shared__ float mins[512];
    __shared__ float red[256];
    __shared__ float part_e[4];
    __shared__ int part_c[4];
    __shared__ float min_e_s;
    __shared__ int copyf_s;
    __shared__ int donef_s;
    __shared__ int cnt_s;
    __shared__ int jidx[512];
    __shared__ float jdel[512];
    const int i0 = 2 * tid, i1 = 2 * tid + 1;
    const int wave = tid >> 6, lane = tid & 63;

    float sm10, sm11, sm20, sm21, h0, h1;
    {
        sm10 = tanhf(lat[(size_t)row * 512 + i0]);
        sm11 = tanhf(lat[(size_t)row * 512 + i1]);
        sm20 = sm10; sm21 = sm11;
        h0 = hmat[(size_t)row * 512 + i0];
        h1 = hmat[(size_t)row * 512 + i1];
    }
    if (tid == 0) { min_e_s = INFINITY; donef_s = 0; cnt_s = 0; }
    __syncthreads();

    for (int k = 1; k <= 512; ++k) {
        float sn0 = fabsf(sm10) * sgnf(h0);
        float sn1 = fabsf(sm11) * sgnf(h1);
        int cy = (sn0 == sm20 && sn1 == sm21) ? 1 : 0;
        if (sn0 != sm10) {
            int p = atomicAdd(&cnt_s, 1);
            jidx[p] = i0; jdel[p] = sn0 - sm10;
        }
        if (sn1 != sm11) {
            int p = atomicAdd(&cnt_s, 1);
            jidx[p] = i1; jdel[p] = sn1 - sm11;
        }
        #pragma unroll
        for (int m = 32; m >= 1; m >>= 1) cy &= __shfl_xor(cy, m, 64);
        if (lane == 0) part_c[wave] = cy;
        __syncthreads();   // flip list complete

        {
            const int c = cnt_s;
            #pragma unroll 8
            for (int t = 0; t < c; ++t) {
                const int j = jidx[t];
                const float d = jdel[t];
                const float2 wvv = *(const float2*)(w + (size_t)j * 512 + i0);
                h0 = fmaf(d, wvv.x, h0);
                h1 = fmaf(d, wvv.y, h1);
            }
        }
        float ep = sn0 * h0 + sn1 * h1;
        #pragma unroll
        for (int m = 32; m >= 1; m >>= 1) ep += __shfl_xor(ep, m, 64);
        if (lane == 0) part_e[wave] = ep;
        __syncthreads();

        if (tid == 0) {
            float e = -(part_e[0] + part_e[1] + part_e[2] + part_e[3]);
            int better = e < min_e_s;
            if (better) min_e_s = e;
            copyf_s = better;
            int fl = part_c[0] & part_c[1] & part_c[2] & part_c[3];
            int fixedp = (cnt_s == 0);
            int cyc = (k >= 2) && fl;
            if (fixedp || cyc) donef_s = 1;
            cnt_s = 0;
        }
        __syncthreads();

        if (copyf_s) { mins[i0] = sn0; mins[i1] = sn1; }
        sm20 = sm10; sm21 = sm11;
        sm10 = sn0;  sm11 = sn1;
        if (donef_s) break;
    }
    __syncthreads();

    const int j = tid & 127, half = tid >> 7;
    {
        const float4* rr = (const float4*)(rep + (size_t)j * 512 + half * 256);
        const float4* ms = (const float4*)(&mins[half * 256]);
        float p = 0.f;
        #pragma unroll 8
        for (int q = 0; q < 64; ++q) {
            float4 rv = rr[q], mv = ms[q];
            p += rv.x * mv.x + rv.y * mv.y + rv.z * mv.z + rv.w * mv.w;
        }
        red[tid] = p;
        __syncthreads();
        float v = 0.f;
        if (tid < 128) { v = fabsf(red[tid] + red[tid + 128]); red[tid] = v; }
        __syncthreads();
        for (int off = 64; off >= 1; off >>= 1) {
            if (tid < off) red[tid] = fmaxf(red[tid], red[tid + off]);
            __syncthreads();
        }
        float mx = red[0];
        __syncthreads();
        float ex = 0.f;
        if (tid < 128) { ex = expf(v - mx); red[tid] = ex; }
        __syncthreads();
        for (int off = 64; off >= 1; off >>= 1) {
            if (tid < off) red[tid] += red[tid + off];
            __syncthreads();
        }
        if (tid < 128) out[(size_t)row * 128 + tid] = ex / red[0];
    }
}

extern "C" void kernel_launch(void* const* d_in, const int* in_sizes, int n_in,
                              void* d_out, int out_size, void* d_ws, size_t ws_size,
                              hipStream_t stream) {
    const float* image = (const float*)d_in[0];
    const float* limg  = (const float*)d_in[1];
    const float* c1w   = (const float*)d_in[2];
    const float* c1b   = (const float*)d_in[3];
    const float* c2w   = (const float*)d_in[4];
    const float* c2b   = (const float*)d_in[5];
    const float* f1w   = (const float*)d_in[6];
    const float* f1b   = (const float*)d_in[7];
    const float* fnw   = (const float*)d_in[8];
    const float* fnb   = (const float*)d_in[9];
    float* out = (float*)d_out;
    float* ws  = (float*)d_ws;

    unsigned short* o1b  = (unsigned short*)ws;        // 1152*12800 us
    unsigned short* out2 = o1b + (size_t)NTOT * 12800; // 2*ASTR bf16
    float* lat  = (float*)(out2 + 2 * ASTR);           // 1024*512
    float* rep  = lat + (size_t)BATCH * 512;           // 128*512
    float* tT   = rep + (size_t)LABEL * 512;           // 512*128
    float* wmat = tT + (size_t)512 * 128;              // 512*512
    float* rho  = wmat + (size_t)512 * 512;            // 1 (+pad)
    unsigned short* Bw2   = (unsigned short*)(rho + 16);   // 2*BSTR bf16
    unsigned short* Bfrag = Bw2 + 2 * BSTR;                // 102,400 bf16
    float* hmat = (float*)(Bfrag + 102400);            // 1024*512 f32
    unsigned short* lat2 = (unsigned short*)(hmat + A2STR);  // 2*A2STR bf16
    unsigned short* fnw2 = lat2 + 2 * A2STR;           // 2*W2STR bf16
    float* logits = (float*)(fnw2 + 2 * W2STR);        // 1024*128 f32
    float* part = (float*)ws;                          // alias o1b (dead after conv2)

    const int prep_total = 102400 + 512 * 3136 + 128 * 512;
    hipLaunchKernelGGL(prep, dim3((prep_total + 255) / 256), dim3(256), 0, stream,
                       c2w, f1w, fnw, Bfrag, Bw2, fnw2);
    hipLaunchKernelGGL(conv1_pool, dim3(NTOT), dim3(256), 0, stream, image, limg, c1w, c1b, o1b);
    hipLaunchKernelGGL(conv2_mfma, dim3(NTOT), dim3(256), 0, stream, o1b, Bfrag, c2b, out2);
    hipLaunchKernelGGL(fc1_mfma, dim3(NTOT / 64, 512 / 64, 7), dim3(256), 0, stream,
                       out2, Bw2, part);
    hipLaunchKernelGGL(fc1_reduce, dim3(NTOT * 512 / 256), dim3(256), 0, stream,
                       part, f1b, lat, lat2, rep);
    hipLaunchKernelGGL(fcn_mfma, dim3(16, 2), dim3(256), 0, stream, lat2, fnw2, logits);
    hipLaunchKernelGGL(fcn_softmax2, dim3(BATCH), dim3(128), 0, stream, logits, fnb,
                       out + (size_t)BATCH * LABEL);
    hipLaunchKernelGGL(rho_kernel, dim3(1), dim3(256), 0, stream, rep, rho);
    hipLaunchKernelGGL(t_kernel, dim3(8, 2), dim3(256), 0, stream, rep, rho, tT);
    hipLaunchKernelGGL(w_kernel, dim3(1024), dim3(256), 0, stream, tT, wmat);
    hipLaunchKernelGGL(hinit, dim3(BATCH / 64, 512 / 64), dim3(256), 0, stream, lat, wmat, hmat);
    hipLaunchKernelGGL(clustering, dim3(BATCH), dim3(256), 0, stream,
                       lat, hmat, wmat, rep, out);
}